// Round 8
// baseline (175.290 us; speedup 1.0000x reference)
//
#include <hip/hip_runtime.h>

#define N_NODES 4096
#define C_CH    128
#define NSPEC   10
#define NCUB    165
#define NQUAD   45
#define NMONO   219   // 165 cubic + 45 quad + 9 linear
#define NBLK    1280  // (s,c) pairs
#define NTILE   4     // node tiles of 1024 per (s,c), worst case 4096

// ---- workspace layout (bytes); total ~8.6 MB ----
#define WS_CNT    0            // 10 ints (species counts)
#define WS_LIST   256          // 10*4096 ints = 163840
#define WS_U3SYM  164096       // 4og*165*4k floats = 10560
#define WS_U2SYM  174656       // 4og*45*2k  floats = 1440
#define WS_F      176096       // 4096*128*4 floats  = 8388608

// ---------------------------------------------------------------------------
// Kernel 1 (round-6, proven): blocks 0..7 build permutation-symmetrized
// U3/U2; block 8 buckets nodes by species with LDS counters.
// ---------------------------------------------------------------------------
__global__ __launch_bounds__(256) void k_prep(
        const float* __restrict__ U3_0e, const float* __restrict__ U3_1o,
        const float* __restrict__ U2_0e, const float* __restrict__ U2_1o,
        const int* __restrict__ specie, int* __restrict__ cnt,
        int* __restrict__ list, float* __restrict__ U3sym,
        float* __restrict__ U2sym) {
    int blk = blockIdx.x;
    int t   = threadIdx.x;

    if (blk == 8) {   // ---- lists part (single block, LDS counters) ----
        __shared__ int scnt[NSPEC];
        if (t < NSPEC) scnt[t] = 0;
        __syncthreads();
        for (int i = t; i < N_NODES; i += 256) {
            int s = specie[i];
            int pos = atomicAdd(&scnt[s], 1);
            list[s * N_NODES + pos] = i;
        }
        __syncthreads();
        if (t < NSPEC) cnt[t] = scnt[t];
        return;
    }

    // ---- prep part: blocks 0..7 ----
    __shared__ unsigned char ta[NCUB], tb[NCUB], td[NCUB], qa[NQUAD], qb[NQUAD];
    if (t < NCUB) {
        int idx = 0, a = 0, b = 0, d = 0;
        for (int a0 = 0; a0 < 9; a0++)
            for (int b0 = a0; b0 < 9; b0++)
                for (int d0 = b0; d0 < 9; d0++) {
                    if (idx == t) { a = a0; b = b0; d = d0; }
                    idx++;
                }
        ta[t] = a; tb[t] = b; td[t] = d;
    } else if (t >= NCUB && t < NCUB + NQUAD) {
        int q = t - NCUB, idx = 0, a = 0, b = 0;
        for (int a0 = 0; a0 < 9; a0++)
            for (int b0 = a0; b0 < 9; b0++) { if (idx == q) { a = a0; b = b0; } idx++; }
        qa[q] = a; qb[q] = b;
    }
    __syncthreads();

    for (int task = blk * 256 + t; task < 2640 + 360; task += 8 * 256) {
        if (task < 2640) {               // cubic: og(4) * m(165) * k(4)
            int og = task / 660;
            int r  = task - og * 660;
            int m  = r >> 2, k = r & 3;
            int a = ta[m], b = tb[m], d = td[m];
            const float* U3 = (og == 0) ? U3_0e : U3_1o;
            int o = (og == 0) ? 0 : og - 1;
            const float* Ub = U3 + (size_t)o * 2916;   // [p][q][i][k] 324/36/4/1
            #define U3AT(p,q,i) Ub[((p)*9+(q))*36 + (i)*4 + k]
            float sum = U3AT(a,b,d) + U3AT(a,d,b) + U3AT(b,a,d)
                      + U3AT(b,d,a) + U3AT(d,a,b) + U3AT(d,b,a);
            #undef U3AT
            float sc = (a == b && b == d) ? (1.f/6.f)
                     : ((a == b || b == d || a == d) ? 0.5f : 1.f);
            U3sym[(og * 165 + m) * 4 + k] = sum * sc;
        } else {                          // quad: og(4) * q(45) * k(2)
            int t2 = task - 2640;
            int og = t2 / 90;
            int r  = t2 - og * 90;
            int q  = r >> 1, k = r & 1;
            int a = qa[q], b = qb[q];
            const float* U2 = (og == 0) ? U2_0e : U2_1o;
            int o = (og == 0) ? 0 : og - 1;
            const float* Ub = U2 + (size_t)o * 162;    // [p][i][k] 18/2/1
            float sum = Ub[(a*9 + b)*2 + k] + Ub[(b*9 + a)*2 + k];
            if (a == b) sum *= 0.5f;
            U2sym[(og * 45 + q) * 2 + k] = sum;
        }
    }
}

// ---------------------------------------------------------------------------
// Kernel 2: coeff-fused main contraction, now 4 NODES PER THREAD.
// DS-pipe analysis: d-loop cost/wave was b64(x,512B)+uniform b128(coeff)
// ~13cyc per 2 nodes; with x in float4 it's spread b128(1KB)+uniform b128
// ~17cyc per 4 nodes -> 1.5x less DS per node, 16 FMAs per coeff broadcast.
// Same per-node FP order as round 5/6 (bitwise-identical f).
// Real loops (#pragma unroll 1) -- the proven no-spill structure.
// Nodes 4*tid+j (contiguous): partial-species waves skip compute via execz.
// ---------------------------------------------------------------------------
__global__ __launch_bounds__(256) void k_main(const float* __restrict__ x,
        const int* __restrict__ cnt, const int* __restrict__ list,
        const float* __restrict__ U3sym, const float* __restrict__ U2sym,
        const float* __restrict__ U1_0e, const float* __restrict__ U1_1o,
        const float* __restrict__ W3_0e, const float* __restrict__ W3_1o,
        const float* __restrict__ W2_0e, const float* __restrict__ W2_1o,
        const float* __restrict__ W1_0e, const float* __restrict__ W1_1o,
        float* __restrict__ fout) {
    __shared__ float  cfs[NMONO * 4];        // 3504 B
    __shared__ float4 xsh[9 * 256];          // 36864 B, [i][tid], 4 nodes/thread
    int bx   = blockIdx.x;
    int tile = bx / NBLK;
    int blk  = bx - tile * NBLK;
    int s = blk >> 7, c = blk & 127;
    int n = cnt[s];
    if (tile * 1024 >= n) return;            // block-uniform exit (before sync)

    int tid = threadIdx.x;

    // ---- coefficient preamble (fused k_coeff, round-6) ----
    for (int e = tid; e < NMONO * 4; e += 256) {
        int m = e >> 2, og = e & 3;
        float val;
        if (m < NCUB) {
            const float* W3 = (og == 0) ? W3_0e : W3_1o;   // [s][k][c] 512/128/1
            const float* u  = U3sym + (og * 165 + m) * 4;
            val = u[0] * W3[s*512 +       c] + u[1] * W3[s*512 + 128 + c]
                + u[2] * W3[s*512 + 256 + c] + u[3] * W3[s*512 + 384 + c];
        } else if (m < NCUB + NQUAD) {
            int q = m - NCUB;
            const float* W2 = (og == 0) ? W2_0e : W2_1o;   // [s][k][c] 256/128/1
            const float* u  = U2sym + (og * 45 + q) * 2;
            val = u[0] * W2[s*256 + c] + u[1] * W2[s*256 + 128 + c];
        } else {
            int l = m - (NCUB + NQUAD);
            const float* U1 = (og == 0) ? U1_0e : U1_1o;   // [o][i][k=1]
            const float* W1 = (og == 0) ? W1_0e : W1_1o;   // [s][1][c]
            int o = (og == 0) ? 0 : og - 1;
            val = U1[o * 9 + l] * W1[s * 128 + c];
        }
        cfs[e] = val;
    }

    // ---- x staging: 4 nodes/thread, xsh[i][tid] = {x_n0..x_n3}[i] ----
    const int* __restrict__ lst = list + s * N_NODES;
    int i0 = tile * 1024 + 4 * tid;
    int b0 = lst[(i0     < n) ? i0     : 0];
    int b1 = lst[(i0 + 1 < n) ? i0 + 1 : 0];
    int b2 = lst[(i0 + 2 < n) ? i0 + 2 : 0];
    int b3 = lst[(i0 + 3 < n) ? i0 + 3 : 0];
    const float* xp0 = x + ((size_t)b0 * C_CH + c) * 9;
    const float* xp1 = x + ((size_t)b1 * C_CH + c) * 9;
    const float* xp2 = x + ((size_t)b2 * C_CH + c) * 9;
    const float* xp3 = x + ((size_t)b3 * C_CH + c) * 9;
    #pragma unroll
    for (int i = 0; i < 9; i++)
        xsh[i * 256 + tid] = make_float4(xp0[i], xp1[i], xp2[i], xp3[i]);
    __syncthreads();

    if (i0 < n) {   // no barriers below: dead lanes/waves skip via exec mask
        const float4* __restrict__ cf4 = (const float4*)cfs;
        float4 a0 = make_float4(0.f, 0.f, 0.f, 0.f);
        float4 a1 = a0, a2 = a0, a3 = a0;
        int mcub = 0, mquad = 0;

        #define FMA4(acc, cf, xv) \
            acc.x = fmaf(cf.x, xv, acc.x); acc.y = fmaf(cf.y, xv, acc.y); \
            acc.z = fmaf(cf.z, xv, acc.z); acc.w = fmaf(cf.w, xv, acc.w);

        #pragma unroll 1
        for (int a = 0; a < 9; a++) {
            float4 xa = xsh[a * 256 + tid];
            {   // linear term
                float4 cl = cf4[210 + a];
                FMA4(a0, cl, xa.x)  FMA4(a1, cl, xa.y)
                FMA4(a2, cl, xa.z)  FMA4(a3, cl, xa.w)
            }
            #pragma unroll 1
            for (int b = a; b < 9; b++) {
                float4 xb = xsh[b * 256 + tid];
                float px = xa.x * xb.x, py = xa.y * xb.y;
                float pz = xa.z * xb.z, pw = xa.w * xb.w;
                {
                    float4 cq = cf4[165 + mquad]; mquad++;
                    FMA4(a0, cq, px)  FMA4(a1, cq, py)
                    FMA4(a2, cq, pz)  FMA4(a3, cq, pw)
                }
                #pragma unroll 1
                for (int d = b; d < 9; d++) {
                    float4 xd = xsh[d * 256 + tid];
                    float4 c3 = cf4[mcub]; mcub++;
                    float qx = px * xd.x, qy = py * xd.y;
                    float qz = pz * xd.z, qw = pw * xd.w;
                    FMA4(a0, c3, qx)  FMA4(a1, c3, qy)
                    FMA4(a2, c3, qz)  FMA4(a3, c3, qw)
                }
            }
        }
        #undef FMA4

        *(float4*)&fout[((size_t)b0 * C_CH + c) * 4] = a0;
        if (i0 + 1 < n) *(float4*)&fout[((size_t)b1 * C_CH + c) * 4] = a1;
        if (i0 + 2 < n) *(float4*)&fout[((size_t)b2 * C_CH + c) * 4] = a2;
        if (i0 + 3 < n) *(float4*)&fout[((size_t)b3 * C_CH + c) * 4] = a3;
    }
}

// ---------------------------------------------------------------------------
// Kernel 3: epilogue linear (round-0/5/6 version, unchanged).
// ---------------------------------------------------------------------------
__global__ __launch_bounds__(256) void k_epi(const float* __restrict__ f,
        const float* __restrict__ W0, const float* __restrict__ W1,
        const float* __restrict__ bias, float* __restrict__ out) {
    __shared__ float smem[128 * 65];        // ftile [c][n(64)+pad]; reused as trbuf [j][n]
    int bx = blockIdx.x;
    int ntile = bx >> 3, jg = bx & 7;       // 64 n-tiles x 8 j-groups of 64
    int n0 = ntile * 64;
    int t  = threadIdx.x;
    int o  = jg >> 1;                        // output component 0..3 (uniform per block)

    #pragma unroll
    for (int r = 0; r < 32; ++r) {
        int flat = r * 256 + t;              // 8192 = 64n * 128c
        int n = flat >> 7, c = flat & 127;
        smem[c * 65 + n] = f[(size_t)(n0 + n) * 512 + c * 4 + o];
    }
    __syncthreads();

    int w    = __builtin_amdgcn_readfirstlane((int)(t >> 6));
    int lane = t & 63;
    int mb   = (jg & 1) * 64 + w * 16;       // wave's m base (uniform)
    const float* __restrict__ Wsel = (o == 0) ? W0 : W1;

    float acc[16];
    #pragma unroll
    for (int jj = 0; jj < 16; jj++) acc[jj] = 0.f;

    #pragma unroll 4
    for (int c = 0; c < 128; ++c) {
        float fv = smem[c * 65 + lane];
        #pragma unroll
        for (int jj = 0; jj < 16; jj++)
            acc[jj] = fmaf(fv, Wsel[c * 128 + mb + jj], acc[jj]);
    }
    __syncthreads();                          // all waves done reading ftile

    const float scale = 0.08838834764831845f; // 1/sqrt(128)
    #pragma unroll
    for (int jj = 0; jj < 16; jj++) {
        float v = acc[jj] * scale;
        if (o == 0) v += bias[mb + jj];
        smem[(w * 16 + jj) * 65 + lane] = v;  // trbuf[j_local][n]
    }
    __syncthreads();

    #pragma unroll
    for (int r = 0; r < 16; ++r) {
        int flat = r * 256 + t;               // 4096 = 64j * 64n
        int jl = flat & 63, n = flat >> 6;
        int m  = (jg & 1) * 64 + jl;
        int col = (o == 0) ? m : (128 + m * 3 + (o - 1));
        out[(size_t)(n0 + n) * 512 + col] = smem[jl * 65 + n];
    }
}

extern "C" void kernel_launch(void* const* d_in, const int* in_sizes, int n_in,
                              void* d_out, int out_size, void* d_ws, size_t ws_size,
                              hipStream_t stream) {
    const float* x     = (const float*)d_in[0];
    const int*   spec  = (const int*)  d_in[1];
    const float* U3_0e = (const float*)d_in[2];
    const float* U2_0e = (const float*)d_in[3];
    const float* U1_0e = (const float*)d_in[4];
    const float* W3_0e = (const float*)d_in[5];
    const float* W2_0e = (const float*)d_in[6];
    const float* W1_0e = (const float*)d_in[7];
    const float* U3_1o = (const float*)d_in[8];
    const float* U2_1o = (const float*)d_in[9];
    const float* U1_1o = (const float*)d_in[10];
    const float* W3_1o = (const float*)d_in[11];
    const float* W2_1o = (const float*)d_in[12];
    const float* W1_1o = (const float*)d_in[13];
    const float* Wlin0 = (const float*)d_in[14];
    const float* Wlin1 = (const float*)d_in[15];
    const float* bias0 = (const float*)d_in[16];
    float* out = (float*)d_out;

    char* ws = (char*)d_ws;
    int*   cnt   = (int*)  (ws + WS_CNT);
    int*   list  = (int*)  (ws + WS_LIST);
    float* U3sym = (float*)(ws + WS_U3SYM);
    float* U2sym = (float*)(ws + WS_U2SYM);
    float* f     = (float*)(ws + WS_F);
    (void)in_sizes; (void)n_in; (void)out_size; (void)ws_size;

    // K1: blocks 0..7 = symmetrize U3/U2; block 8 = species bucketing.
    hipLaunchKernelGGL(k_prep, dim3(9), dim3(256), 0, stream,
                       U3_0e, U3_1o, U2_0e, U2_1o, spec, cnt, list, U3sym, U2sym);
    // K2: coeff-fused contraction, 4 nodes/thread. Dead tiles exit instantly.
    hipLaunchKernelGGL(k_main, dim3(NBLK * NTILE), dim3(256), 0, stream,
                       x, cnt, list, U3sym, U2sym, U1_0e, U1_1o,
                       W3_0e, W3_1o, W2_0e, W2_1o, W1_0e, W1_1o, f);
    // K3: epilogue linear.
    hipLaunchKernelGGL(k_epi, dim3(512), dim3(256), 0, stream,
                       f, Wlin0, Wlin1, bias0, out);
}